// Round 8
// baseline (62.566 us; speedup 1.0000x reference)
//
#include <hip/hip_runtime.h>
#include <hip/hip_bf16.h>

#define BB 64
#define NN 96
#define FF 16
#define HH 128
#define KK 64
#define LL 3
#define CUTOFF_F 10.0f
#define GAMMA_F 10.0f

#define WT_BLOCKS 99          // 3 layers * 33 blocks (2 rows of W3 each, 65 rows/layer)
#define CNT_BLOCKS BB

// ---------------------------------------------------------------------------
// pre_kernel:
//   [0,99):   rows {2i,2i+1} of W2[l]=Wrbf@Wpair (row 64 = bias row) staged in
//             LDS, then W3 rows = W2row@Wa1 (row 64 -> c3).
//   [99,163): cnt[b] = #valid atoms; zero out[b] (atomic target in chain)
// ---------------------------------------------------------------------------
__global__ __launch_bounds__(256) void pre_kernel(
    const float* __restrict__ Wrbf, const float* __restrict__ brbf,
    const float* __restrict__ Wpair, const float* __restrict__ bpair,
    const float* __restrict__ Wa1,
    const int* __restrict__ batch,
    float* __restrict__ W3, float* __restrict__ c3,
    float* __restrict__ cnt, float* __restrict__ out)
{
    const int bid = blockIdx.x;
    const int tid = threadIdx.x;
    if (bid < WT_BLOCKS) {
        __shared__ float sW2[2][HH];
        const int l    = bid / 33;
        const int r0   = (bid % 33) * 2;
        const int half = tid >> 7;
        const int h    = tid & 127;
        const int kk   = r0 + half;       // 0..65 (65 inactive)
        const bool active = (kk <= KK);
        if (active) {
            const float* Wp = Wpair + l * HH * HH + h;
            const float* arow;
            float acc;
            if (kk < KK) { arow = Wrbf + (l * KK + kk) * HH; acc = 0.f; }
            else         { arow = brbf + l * HH;             acc = bpair[l * HH + h]; }
            #pragma unroll 8
            for (int m = 0; m < HH; ++m) acc += arow[m] * Wp[m * HH];
            sW2[half][h] = acc;
        }
        __syncthreads();
        if (active) {
            const float* Wa = Wa1 + l * HH * HH + h;
            const float* row = sW2[half];
            float a3 = 0.f;
            #pragma unroll 8
            for (int m = 0; m < HH; ++m) a3 += row[m] * Wa[m * HH];
            if (kk < KK) W3[(l * KK + kk) * HH + h] = a3;
            else         c3[l * HH + h] = a3;
        }
    } else {
        int b = bid - WT_BLOCKS;
        __shared__ int c[4];
        bool v = (tid < NN) && (batch[b * NN + tid] != -1);
        unsigned long long m = __ballot(v);
        if ((tid & 63) == 0) c[tid >> 6] = __popcll(m);
        __syncthreads();
        if (tid == 0) {
            cnt[b] = (float)(c[0] + c[1] + c[2] + c[3]);
            out[b] = 0.f;                 // zero the atomic target each call
        }
    }
}

// ---------------------------------------------------------------------------
// chain_kernel: fused S-compute + per-atom MLP chain.
// Block = 256 threads, AT=12 atoms, grid 512 = 2 blocks/CU (2 waves/SIMD).
// Thread tile: 2 channels x 3 atoms. q=tid&15, g=(tid>>4)&3, wv=tid>>6.
//   channels c0 = 32*wv + 2*q (wave owns a 32-ch slice -> weight lines read
//   once per block), atoms 3g..3g+2 at LDS cols 4g..4g+2 (SSW=20 padding).
// Weights read directly from global (L2-resident, coalesced float2);
// only atom operands (S^T, t) live in LDS. No DMA, no vmcnt drains.
// ---------------------------------------------------------------------------
#define AT 12
#define SSW 20   // padded row width: 80B rows keep b128 alignment, spread banks

__device__ __forceinline__ float silu1(float v) { return v / (1.f + __expf(-v)); }

// acc[2a+i]: atom a (0..2), channel i (0..1)
#define FMA6(ACC, W2, T4)                                     \
    do {                                                      \
        ACC[0] += (W2).x * (T4).x; ACC[1] += (W2).y * (T4).x; \
        ACC[2] += (W2).x * (T4).y; ACC[3] += (W2).y * (T4).y; \
        ACC[4] += (W2).x * (T4).z; ACC[5] += (W2).y * (T4).z; \
    } while (0)

__global__ __launch_bounds__(256, 2) void chain_kernel(
    const float* __restrict__ X, const float* __restrict__ R,
    const float* __restrict__ We, const float* __restrict__ be,
    const float* __restrict__ ba1, const float* __restrict__ Wa2,
    const float* __restrict__ ba2, const float* __restrict__ Wo1,
    const float* __restrict__ bo1, const float* __restrict__ Wo2,
    const float* __restrict__ bo2, const float* __restrict__ W3,
    const float* __restrict__ c3, const float* __restrict__ cnt,
    float* __restrict__ out)
{
    __shared__ __align__(16) float sS[KK][SSW];   // 5 KB   (S^T, persists)
    __shared__ __align__(16) float tb[HH][SSW];   // 10 KB  (t / h staging; sD+sRf early)
    __shared__ __align__(16) float sX[FF][SSW];   // 1.25 KB
    __shared__ float po[4][AT];

    const int tid = threadIdx.x;
    const int q   = tid & 15;
    const int g   = (tid >> 4) & 3;      // atom triple: atoms 3g..3g+2
    const int wv  = tid >> 6;
    const int c0  = wv * 32 + q * 2;     // channels c0, c0+1
    const int g4  = g * 4;
    const int a0  = blockIdx.x * AT;     // 96 % 12 == 0 -> block within one molecule
    const int b   = a0 / NN;
    const int lbase = a0 - b * NN;       // molecule-local first atom
    const float cb = cnt[b];
    const int nv  = (int)cb;             // valid atoms are prefix 0..nv-1 (local)

    // scratch aliased into tb (dead before first tb write)
    float* sD  = &tb[0][0];              // AT*NN = 1152 floats: distances
    float* sRf = sD + AT * NN;           // 288 floats: molecule R

    // ---- stage molecule R, X^T ----
    for (int t = tid; t < NN * 3; t += 256) sRf[t] = R[b * NN * 3 + t];
    for (int t = tid; t < AT * FF; t += 256) {
        int a = t >> 4, f = t & 15;
        sX[f][(a / 3) * 4 + a % 3] = X[(a0 + a) * FF + f];
    }
    __syncthreads();

    // ---- phase 1: distance table D[j][i] ----
    for (int e = tid; e < AT * NN; e += 256) {
        int j = e / NN, i = e - j * NN;
        float dx = sRf[i * 3 + 0] - sRf[(lbase + j) * 3 + 0];
        float dy = sRf[i * 3 + 1] - sRf[(lbase + j) * 3 + 1];
        float dz = sRf[i * 3 + 2] - sRf[(lbase + j) * 3 + 2];
        sD[e] = sqrtf(dx * dx + dy * dy + dz * dz);
    }
    __syncthreads();

    // ---- phase 2: sS[k][col(j)] = sum_{i<nv} exp(-g*(D[j][i]-ck)^2) ----
    {
        const int k  = tid & 63;
        const int w2 = tid >> 6;
        const float ck = (float)k * (CUTOFF_F / (float)(KK - 1));
        #pragma unroll
        for (int r = 0; r < 3; ++r) {
            int j = w2 * 3 + r;          // wave-uniform
            int col = (j / 3) * 4 + j % 3;
            if (lbase + j >= nv) { sS[k][col] = 0.f; continue; }
            const float* Dr = sD + j * NN;
            float acc = 0.f;
            for (int i = 0; i < nv; ++i) {
                float u = Dr[i] - ck;
                acc += __expf(-GAMMA_F * u * u);
            }
            sS[k][col] = acc;
        }
    }

    // ---- embedding: h = X@We + be ----
    float h[6];
    {
        float acc[6] = {0, 0, 0, 0, 0, 0};
        const float* wp = We + c0;
        #pragma unroll
        for (int f = 0; f < FF; ++f) {
            float2 w2 = *(const float2*)(wp + f * HH);
            float4 x4 = *(const float4*)&sX[f][g4];
            FMA6(acc, w2, x4);
        }
        float2 be2 = *(const float2*)&be[c0];
        h[0] = acc[0] + be2.x; h[1] = acc[1] + be2.y;
        h[2] = acc[2] + be2.x; h[3] = acc[3] + be2.y;
        h[4] = acc[4] + be2.x; h[5] = acc[5] + be2.y;
    }

    __syncthreads();   // S0: sS ready; sD/sRf dead

    // ---- layers ----
    for (int l = 0; l < LL; ++l) {
        // GEMM1: acc = S @ W3[l]  (weights global, atoms LDS broadcast)
        float acc[6] = {0, 0, 0, 0, 0, 0};
        {
            const float* wp = W3 + l * KK * HH + c0;
            #pragma unroll 8
            for (int k = 0; k < KK; ++k) {
                float2 w2 = *(const float2*)(wp + k * HH);
                float4 t4 = *(const float4*)&sS[k][g4];
                FMA6(acc, w2, t4);
            }
        }
        float2 c32  = *(const float2*)&c3[l * HH + c0];
        float2 ba12 = *(const float2*)&ba1[l * HH + c0];
        float t0 = silu1(acc[0] + cb * c32.x + ba12.x);
        float t1 = silu1(acc[1] + cb * c32.y + ba12.y);
        float t2 = silu1(acc[2] + cb * c32.x + ba12.x);
        float t3 = silu1(acc[3] + cb * c32.y + ba12.y);
        float t4v = silu1(acc[4] + cb * c32.x + ba12.x);
        float t5 = silu1(acc[5] + cb * c32.y + ba12.y);

        __syncthreads();   // S1: previous tb readers done
        *(float4*)&tb[c0 + 0][g4] = make_float4(t0, t2, t4v, 0.f);
        *(float4*)&tb[c0 + 1][g4] = make_float4(t1, t3, t5, 0.f);
        __syncthreads();   // S2: tb visible

        // GEMM2: h += t @ Wa2[l]
        float acc2[6] = {0, 0, 0, 0, 0, 0};
        {
            const float* wq = Wa2 + l * HH * HH + c0;
            #pragma unroll 8
            for (int m = 0; m < HH; ++m) {
                float2 w2 = *(const float2*)(wq + m * HH);
                float4 t4 = *(const float4*)&tb[m][g4];
                FMA6(acc2, w2, t4);
            }
        }
        float2 ba22 = *(const float2*)&ba2[l * HH + c0];
        h[0] += acc2[0] + ba22.x; h[1] += acc2[1] + ba22.y;
        h[2] += acc2[2] + ba22.x; h[3] += acc2[3] + ba22.y;
        h[4] += acc2[4] + ba22.x; h[5] += acc2[5] + ba22.y;
    }

    // ---- output head ----
    __syncthreads();   // S3: prior tb readers done
    *(float4*)&tb[c0 + 0][g4] = make_float4(h[0], h[2], h[4], 0.f);
    *(float4*)&tb[c0 + 1][g4] = make_float4(h[1], h[3], h[5], 0.f);
    __syncthreads();   // S4: tb visible

    float acc[6] = {0, 0, 0, 0, 0, 0};
    {
        const float* wp = Wo1 + c0;
        #pragma unroll 8
        for (int m = 0; m < HH; ++m) {
            float2 w2 = *(const float2*)(wp + m * HH);
            float4 t4 = *(const float4*)&tb[m][g4];
            FMA6(acc, w2, t4);
        }
    }
    float2 bo12 = *(const float2*)&bo1[c0];
    float2 wo22 = *(const float2*)&Wo2[c0];
    float p[3];
    #pragma unroll
    for (int a = 0; a < 3; ++a) {
        p[a] = silu1(acc[2 * a + 0] + bo12.x) * wo22.x
             + silu1(acc[2 * a + 1] + bo12.y) * wo22.y;
    }
    // reduce across the 16 q-lanes of each (wv,g) group
    #pragma unroll
    for (int a = 0; a < 3; ++a) {
        float r = p[a];
        r += __shfl_down(r, 8); r += __shfl_down(r, 4);
        r += __shfl_down(r, 2); r += __shfl_down(r, 1);
        p[a] = r;
    }
    if (q == 0) {
        #pragma unroll
        for (int a = 0; a < 3; ++a) po[wv][3 * g + a] = p[a];
    }
    __syncthreads();
    if (tid == 0) {
        float bo2v = bo2[0];
        float sum = 0.f;
        #pragma unroll
        for (int j = 0; j < AT; ++j) {
            if (lbase + j < nv)
                sum += po[0][j] + po[1][j] + po[2][j] + po[3][j] + bo2v;
        }
        atomicAdd(out + b, sum / cb);
    }
}

extern "C" void kernel_launch(void* const* d_in, const int* in_sizes, int n_in,
                              void* d_out, int out_size, void* d_ws, size_t ws_size,
                              hipStream_t stream) {
    const float* X     = (const float*)d_in[0];
    const float* R     = (const float*)d_in[1];
    const int*   batch = (const int*)  d_in[2];
    const float* We    = (const float*)d_in[3];
    const float* be    = (const float*)d_in[4];
    const float* Wrbf  = (const float*)d_in[5];
    const float* brbf  = (const float*)d_in[6];
    const float* Wpair = (const float*)d_in[7];
    const float* bpair = (const float*)d_in[8];
    const float* Wa1   = (const float*)d_in[9];
    const float* ba1   = (const float*)d_in[10];
    const float* Wa2   = (const float*)d_in[11];
    const float* ba2   = (const float*)d_in[12];
    const float* Wo1   = (const float*)d_in[13];
    const float* bo1   = (const float*)d_in[14];
    const float* Wo2   = (const float*)d_in[15];
    const float* bo2   = (const float*)d_in[16];

    float* w   = (float*)d_ws;
    float* W3  = w;                        // L*K*H = 24576
    float* c3  = W3 + LL * KK * HH;        // L*H   = 384
    float* cnt = c3 + LL * HH;             // B     = 64
    float* out = (float*)d_out;

    hipLaunchKernelGGL(pre_kernel, dim3(WT_BLOCKS + CNT_BLOCKS), dim3(256),
                       0, stream, Wrbf, brbf, Wpair, bpair, Wa1, batch,
                       W3, c3, cnt, out);
    hipLaunchKernelGGL(chain_kernel, dim3(BB * NN / AT), dim3(256), 0, stream,
                       X, R, We, be, ba1, Wa2, ba2, Wo1, bo1, Wo2, bo2,
                       W3, c3, cnt, out);
}